// Round 6
// baseline (164.759 us; speedup 1.0000x reference)
//
#include <hip/hip_runtime.h>
#include <math.h>

#define E_TYPES 20
#define NBLK 2
#define NANG 7
#define CS 384
#define CH 128
#define N_TOK (8 * 2048)
#define TOK 32
#define TPB 256
#define KC 128
#define MAX_TILES (N_TOK / TOK + E_TYPES)   // 532
#define PADN 2048                           // per-type perm region (ints)

// ---- workspace: int control region ----
#define CNT_OFF 0            // 20 counts (written by prep block 63)
#define PERM_OFF 64          // 20 x PADN fixed per-type regions
// ---- workspace: fragment-packed split-bf16 weights (byte offsets) ----
#define WT1_OFF (256 * 1024)                 // phase-1 concat [768x128] per e
#define WT1_SZ  (20 * 8 * 24 * 2048)         // e x nt(8) x kb(24) x (hi 1KB + lo 1KB)
#define WTR_OFF (WT1_OFF + WT1_SZ)           // residual: e x m4(4) x nt(8) x kb(4)

typedef __attribute__((ext_vector_type(8))) short bfrag;
typedef __attribute__((ext_vector_type(4))) float f32x4;

__device__ __forceinline__ void split_bf16(float x, unsigned short& h, unsigned short& l) {
    unsigned int u = __float_as_uint(x);
    unsigned int hb = (u + 0x7FFFu + ((u >> 16) & 1u)) & 0xFFFF0000u;
    h = (unsigned short)(hb >> 16);
    float r = x - __uint_as_float(hb);
    unsigned int v = __float_as_uint(r);
    l = (unsigned short)((v + 0x7FFFu + ((v >> 16) & 1u)) >> 16);
}

// ============ prep: fused scatter (blocks 0..63) + weight transpose ============
// Transpose blocks: each wave handles one 32k x 128n tile; coalesced float4
// reads -> LDS split-bf16 planes -> fragment-order readback -> coalesced
// 16B/lane writes in the exact layout angle_main loads (validated round 5).
__global__ __launch_bounds__(TPB)
void prep_k(const float* __restrict__ Win, const float* __restrict__ Winit,
            const float* __restrict__ Wb1, const float* __restrict__ Wb2,
            const int* __restrict__ aatype, int* __restrict__ wsI,
            unsigned short* __restrict__ wt)
{
    __shared__ unsigned short tp[4][2][32][134];   // [wave][hi/lo][k][n], pad 134
    __shared__ int lh[E_TYPES], lcur[E_TYPES];
    int bid = blockIdx.x, t = threadIdx.x;

    if (bid < 64) {   // ---- deterministic scatter, no global atomics ----
        if (t < E_TYPES) { lh[t] = 0; lcur[t] = 0; }
        __syncthreads();
        for (int i = t; i < bid * 256; i += 256) atomicAdd(&lh[aatype[i]], 1);
        __syncthreads();
        int idx = bid * 256 + t;
        int e = aatype[idx];
        int r = lh[e] + atomicAdd(&lcur[e], 1);   // any within-type order is valid
        if (r < PADN) wsI[PERM_OFF + e * PADN + r] = idx;
        if (bid == 63) {
            __syncthreads();
            if (t < E_TYPES) wsI[CNT_OFF + t] = lh[t] + lcur[t];
        }
        return;
    }

    int w = t >> 6, lane = t & 63, lane15 = lane & 15, quad = lane >> 4;
    int wid = (bid - 64) * 4 + w;      // 0..799 tiles
    const float* srcbase;
    int phase1, e, kt, m4 = 0;
    if (wid < 480) {                   // phase-1: e(20) x kt(24)
        phase1 = 1;
        e = wid / 24; kt = wid % 24;
        srcbase = (kt < 12) ? Win   + ((size_t)e * CS + kt * 32) * CH
                            : Winit + ((size_t)e * CS + (kt - 12) * 32) * CH;
    } else {                           // residual: e(20) x m4(4) x kt(4)
        phase1 = 0;
        int rid = wid - 480;
        e = rid >> 4; m4 = (rid >> 2) & 3; kt = rid & 3;
        const float* W = (m4 & 1) ? Wb2 : Wb1;
        srcbase = W + (((size_t)e * NBLK + (m4 >> 1)) * CH + kt * 32) * CH;
    }

    // coalesced load + split into LDS planes
    #pragma unroll 4
    for (int i = 0; i < 16; i++) {
        int idx = i * 64 + lane;
        int row = idx >> 5, c4 = idx & 31;
        float4 v = *(const float4*)(srcbase + (size_t)row * CH + c4 * 4);
        ushort4 hv, lv;
        split_bf16(v.x, hv.x, lv.x);
        split_bf16(v.y, hv.y, lv.y);
        split_bf16(v.z, hv.z, lv.z);
        split_bf16(v.w, hv.w, lv.w);
        *(ushort4*)&tp[w][0][row][c4 * 4] = hv;
        *(ushort4*)&tp[w][1][row][c4 * 4] = lv;
    }
    // fragment-order readback (same element mapping as round-5 prep: verified)
    #pragma unroll
    for (int nt = 0; nt < 8; nt++) {
        bfrag hb, lb;
        #pragma unroll
        for (int j = 0; j < 8; j++) {
            hb[j] = (short)tp[w][0][quad * 8 + j][nt * 16 + lane15];
            lb[j] = (short)tp[w][1][quad * 8 + j][nt * 16 + lane15];
        }
        size_t blk = phase1 ? (size_t)((e * 8 + nt) * 24 + kt)
                            : (size_t)((((e * 4 + m4) * 8) + nt) * 4 + kt);
        unsigned short* dst = wt + (phase1 ? WT1_OFF / 2 : WTR_OFF / 2)
                              + blk * 1024 + lane * 8;
        *(bfrag*)dst = hb;
        *(bfrag*)(dst + 512) = lb;
    }
}

#define MFMA(a, b, c) __builtin_amdgcn_mfma_f32_16x16x32_bf16((a), (b), (c), 0, 0, 0)

// A-fragment LDS layout: fragment-major, [plane][(ks*4+quad)*32 + tok] x 16B.
// ds_read_b128 across the wave touches 64 contiguous 16B chunks -> conflict-free.
__global__ __launch_bounds__(TPB)
void angle_main(const float* __restrict__ s, const float* __restrict__ si,
                const float* __restrict__ b_in, const float* __restrict__ b_init2,
                const float* __restrict__ bb1, const float* __restrict__ bb2,
                const float* __restrict__ Wout, const float* __restrict__ b_out,
                const int* __restrict__ wsI, const unsigned short* __restrict__ wt,
                float* __restrict__ out)
{
    __shared__ __align__(16) unsigned short Afrag[2][2][512][8];  // [buf][hi/lo][fi][8]
    __shared__ float Hf[TOK][132];
    __shared__ float Of[TOK][16];
    __shared__ int ptok[TOK];
    __shared__ int poffs[E_TYPES + 1];

    int t = threadIdx.x;
    if (t == 0) {
        int off = 0;
        for (int e = 0; e < E_TYPES; e++) {
            poffs[e] = off;
            off += (wsI[CNT_OFF + e] + TOK - 1) & ~(TOK - 1);
        }
        poffs[E_TYPES] = off;
    }
    __syncthreads();

    int pos = blockIdx.x * TOK;
    if (pos >= poffs[E_TYPES]) return;
    int e = 0;
    while (e < E_TYPES - 1 && pos >= poffs[e + 1]) e++;
    int n = wsI[CNT_OFF + e] - (pos - poffs[e]);
    if (n > TOK) n = TOK;
    if (t < TOK)
        ptok[t] = wsI[PERM_OFF + e * PADN + (pos - poffs[e]) + ((t < n) ? t : 0)];
    __syncthreads();

    int w = t >> 6, lane = t & 63, lane15 = lane & 15, quad = lane >> 4;
    int nc0 = (2 * w) * 16 + lane15, nc1 = nc0 + 16;

    const bfrag* wt1 = (const bfrag*)((const char*)wt + WT1_OFF);
    const bfrag* wtr = (const bfrag*)((const char*)wt + WTR_OFF);

    f32x4 acc[2][2];   // [m-tile][n-tile]; C: col=lane15, row=quad*4+reg (verified)
    {
        float bv0 = b_in[e * CH + nc0] + b_init2[e * CH + nc0];
        float bv1 = b_in[e * CH + nc1] + b_init2[e * CH + nc1];
        #pragma unroll
        for (int mt = 0; mt < 2; mt++) {
            acc[mt][0] = (f32x4){bv0, bv0, bv0, bv0};
            acc[mt][1] = (f32x4){bv1, bv1, bv1, bv1};
        }
    }

    // staging ids: thread t loads token row t>>3, col group t&7 (4 float4s)
    int stok = t >> 3, sc = t & 7;
    const float* rowp_s  = s  + (size_t)ptok[stok] * CS;
    const float* rowp_si = si + (size_t)ptok[stok] * CS;

    float4 pf[2][4];
    #pragma unroll
    for (int q = 0; q < 4; q++)
        pf[0][q] = *(const float4*)(rowp_s + sc * 4 + 32 * q);

    // ---- phase 1: h = [relu(s) relu(si)] @ [Win;Winit] + biases, K=768 ----
    #pragma unroll
    for (int c = 0; c < 6; c++) {
        int buf = c & 1;
        __syncthreads();   // buf's previous readers (chunk c-2) done
        #pragma unroll
        for (int q = 0; q < 4; q++) {
            float4 v = pf[buf][q];
            ushort4 hv, lv;
            split_bf16(fmaxf(v.x, 0.f), hv.x, lv.x);
            split_bf16(fmaxf(v.y, 0.f), hv.y, lv.y);
            split_bf16(fmaxf(v.z, 0.f), hv.z, lv.z);
            split_bf16(fmaxf(v.w, 0.f), hv.w, lv.w);
            int fi = (q * 4 + (sc >> 1)) * 32 + stok;
            *(ushort4*)&Afrag[buf][0][fi][(sc & 1) * 4] = hv;
            *(ushort4*)&Afrag[buf][1][fi][(sc & 1) * 4] = lv;
        }
        if (c + 1 < 6) {
            const float* rp = ((c + 1) < 3 ? rowp_s : rowp_si) + ((c + 1) % 3) * KC;
            #pragma unroll
            for (int q = 0; q < 4; q++)
                pf[(c + 1) & 1][q] = *(const float4*)(rp + sc * 4 + 32 * q);
        }
        __syncthreads();   // buf ready
        #pragma unroll
        for (int ks = 0; ks < 4; ks++) {
            int kb = c * 4 + ks;
            int fib = (ks * 4 + quad) * 32;
            bfrag ah0 = *(const bfrag*)&Afrag[buf][0][fib + lane15][0];
            bfrag ah1 = *(const bfrag*)&Afrag[buf][0][fib + 16 + lane15][0];
            bfrag al0 = *(const bfrag*)&Afrag[buf][1][fib + lane15][0];
            bfrag al1 = *(const bfrag*)&Afrag[buf][1][fib + 16 + lane15][0];
            size_t b0 = ((size_t)(e * 8 + 2 * w) * 24 + kb) * 128;
            size_t b1 = ((size_t)(e * 8 + 2 * w + 1) * 24 + kb) * 128;
            bfrag bh0 = wt1[b0 + lane], bl0 = wt1[b0 + 64 + lane];
            bfrag bh1 = wt1[b1 + lane], bl1 = wt1[b1 + 64 + lane];
            acc[0][0] = MFMA(ah0, bh0, acc[0][0]);
            acc[0][0] = MFMA(ah0, bl0, acc[0][0]);
            acc[0][0] = MFMA(al0, bh0, acc[0][0]);
            acc[0][1] = MFMA(ah0, bh1, acc[0][1]);
            acc[0][1] = MFMA(ah0, bl1, acc[0][1]);
            acc[0][1] = MFMA(al0, bh1, acc[0][1]);
            acc[1][0] = MFMA(ah1, bh0, acc[1][0]);
            acc[1][0] = MFMA(ah1, bl0, acc[1][0]);
            acc[1][0] = MFMA(al1, bh0, acc[1][0]);
            acc[1][1] = MFMA(ah1, bh1, acc[1][1]);
            acc[1][1] = MFMA(ah1, bl1, acc[1][1]);
            acc[1][1] = MFMA(al1, bh1, acc[1][1]);
        }
    }

    // ---- 2 residual blocks (A-frags in buf 0, fragment-major) ----
    #pragma unroll
    for (int b = 0; b < NBLK; b++) {
        f32x4 a2[2][2];
        #pragma unroll
        for (int stage = 0; stage < 2; stage++) {
            int g = 2 * b + stage;
            __syncthreads();   // prior Afrag readers done
            #pragma unroll
            for (int mt = 0; mt < 2; mt++)
                #pragma unroll
                for (int nl = 0; nl < 2; nl++) {
                    f32x4 v = (stage == 0) ? acc[mt][nl] : a2[mt][nl];
                    int nn = (2 * w + nl) * 16 + lane15;
                    int fib = ((nn >> 5) * 4 + ((nn >> 3) & 3)) * 32;
                    int j = nn & 7;
                    #pragma unroll
                    for (int r = 0; r < 4; r++) {
                        int m = mt * 16 + quad * 4 + r;
                        unsigned short hh, ll;
                        split_bf16(fmaxf(v[r], 0.f), hh, ll);
                        Afrag[0][0][fib + m][j] = hh;
                        Afrag[0][1][fib + m][j] = ll;
                    }
                }
            __syncthreads();

            const float* bias = (stage == 0) ? bb1 : bb2;
            f32x4 an[2][2];
            {
                float bv0 = bias[(e * NBLK + b) * CH + nc0];
                float bv1 = bias[(e * NBLK + b) * CH + nc1];
                #pragma unroll
                for (int mt = 0; mt < 2; mt++) {
                    an[mt][0] = (f32x4){bv0, bv0, bv0, bv0};
                    an[mt][1] = (f32x4){bv1, bv1, bv1, bv1};
                }
            }
            #pragma unroll
            for (int ks = 0; ks < 4; ks++) {
                int fib = (ks * 4 + quad) * 32;
                bfrag ah0 = *(const bfrag*)&Afrag[0][0][fib + lane15][0];
                bfrag ah1 = *(const bfrag*)&Afrag[0][0][fib + 16 + lane15][0];
                bfrag al0 = *(const bfrag*)&Afrag[0][1][fib + lane15][0];
                bfrag al1 = *(const bfrag*)&Afrag[0][1][fib + 16 + lane15][0];
                size_t b0 = ((size_t)((e * 4 + g) * 8 + 2 * w) * 4 + ks) * 128;
                size_t b1 = ((size_t)((e * 4 + g) * 8 + 2 * w + 1) * 4 + ks) * 128;
                bfrag bh0 = wtr[b0 + lane], bl0 = wtr[b0 + 64 + lane];
                bfrag bh1 = wtr[b1 + lane], bl1 = wtr[b1 + 64 + lane];
                an[0][0] = MFMA(ah0, bh0, an[0][0]);
                an[0][0] = MFMA(ah0, bl0, an[0][0]);
                an[0][0] = MFMA(al0, bh0, an[0][0]);
                an[0][1] = MFMA(ah0, bh1, an[0][1]);
                an[0][1] = MFMA(ah0, bl1, an[0][1]);
                an[0][1] = MFMA(al0, bh1, an[0][1]);
                an[1][0] = MFMA(ah1, bh0, an[1][0]);
                an[1][0] = MFMA(ah1, bl0, an[1][0]);
                an[1][0] = MFMA(al1, bh0, an[1][0]);
                an[1][1] = MFMA(ah1, bh1, an[1][1]);
                an[1][1] = MFMA(ah1, bl1, an[1][1]);
                an[1][1] = MFMA(al1, bh1, an[1][1]);
            }
            if (stage == 0) {
                #pragma unroll
                for (int mt = 0; mt < 2; mt++)
                    #pragma unroll
                    for (int nl = 0; nl < 2; nl++) a2[mt][nl] = an[mt][nl];
            } else {
                #pragma unroll
                for (int mt = 0; mt < 2; mt++)
                    #pragma unroll
                    for (int nl = 0; nl < 2; nl++) acc[mt][nl] += an[mt][nl];
            }
        }
    }

    // ---- epilogue: relu(h) fp32 -> LDS ----
    __syncthreads();
    #pragma unroll
    for (int mt = 0; mt < 2; mt++)
        #pragma unroll
        for (int nl = 0; nl < 2; nl++) {
            f32x4 v = acc[mt][nl];
            int nn = (2 * w + nl) * 16 + lane15;
            #pragma unroll
            for (int r = 0; r < 4; r++)
                Hf[mt * 16 + quad * 4 + r][nn] = fmaxf(v[r], 0.f);
        }
    __syncthreads();

    // ---- out = relu(h) @ Wout + b_out (128 -> 14) ----
    const float* WoutE = Wout + (size_t)e * CH * (NANG * 2);
    const float* boutE = b_out + (size_t)e * (NANG * 2);
    for (int idx = t; idx < n * (NANG * 2); idx += TPB) {
        int i = idx / (NANG * 2);
        int o = idx % (NANG * 2);
        float v = boutE[o];
        #pragma unroll 4
        for (int k = 0; k < CH; k++)
            v = fmaf(Hf[i][k], WoutE[(size_t)k * (NANG * 2) + o], v);
        Of[i][o] = v;
    }
    __syncthreads();

    // ---- pair-normalize and store ----
    for (int idx = t; idx < n * NANG; idx += TPB) {
        int i = idx / NANG;
        int a = idx % NANG;
        float x = Of[i][2 * a];
        float y = Of[i][2 * a + 1];
        float nr = fmaxf(sqrtf(x * x + y * y), 1e-12f);
        size_t base = (size_t)ptok[i] * (NANG * 2) + 2 * a;
        out[base]     = x / nr;
        out[base + 1] = y / nr;
    }
}

extern "C" void kernel_launch(void* const* d_in, const int* in_sizes, int n_in,
                              void* d_out, int out_size, void* d_ws, size_t ws_size,
                              hipStream_t stream) {
    const float* s       = (const float*)d_in[0];
    const float* s_init  = (const float*)d_in[1];
    const int*   aatype  = (const int*)d_in[2];
    const float* Win     = (const float*)d_in[3];
    const float* b_in    = (const float*)d_in[4];
    const float* Winit   = (const float*)d_in[5];
    const float* b_init2 = (const float*)d_in[6];
    const float* Wb1     = (const float*)d_in[7];
    const float* bb1     = (const float*)d_in[8];
    const float* Wb2     = (const float*)d_in[9];
    const float* bb2     = (const float*)d_in[10];
    const float* Wout    = (const float*)d_in[11];
    const float* b_out   = (const float*)d_in[12];
    int* wsI = (int*)d_ws;
    unsigned short* wt = (unsigned short*)d_ws;
    float* out = (float*)d_out;

    hipLaunchKernelGGL(prep_k, dim3(64 + 200), dim3(TPB), 0, stream,
                       Win, Winit, Wb1, Wb2, aatype, wsI, wt);
    hipLaunchKernelGGL(angle_main, dim3(MAX_TILES), dim3(TPB), 0, stream,
                       s, s_init, b_in, b_init2, bb1, bb2, Wout, b_out,
                       wsI, wt, out);
}